// Round 7
// baseline (397.652 us; speedup 1.0000x reference)
//
#include <hip/hip_runtime.h>
#include <cstdint>
#include <cmath>

#define BB   4
#define NK   4000
#define NKP  (BB*NK)      // 16000 keypoints total
#define CH   128
#define HH   240
#define WW   320
#define HWSZ (HH*WW)
#define NPOS 8

typedef __attribute__((ext_vector_type(8))) short short8;
typedef __attribute__((ext_vector_type(4))) float f32x4;

// ws layout (bytes):
//   feats_bf : 128000*128*2 = 32,768,000 @ 0
//   pos      : 16000*8*2*4  = 1,024,000  @ 32,768,000
//   sfT      : 65,536  @ 65,536,000  [legacy]
//   w1T      : 73,728  @ 65,601,536
//   xcl      : 157,286,400 @ 65,675,264   [NHWC x; dead after k_gather]
//     part   : 4*16000*128*4 = 32,768,000 @ 65,675,264   [aliases xcl]
//   sfB      : 32,768  @ 222,961,664  [bf16 MFMA-packed sf_w^T]
//   agB      : 262,144 @ 222,994,432  [bf16 MFMA-packed agg_w]
static constexpr size_t OFF_POS  = 32768000;
static constexpr size_t OFF_SFT  = 65536000;
static constexpr size_t OFF_W1T  = 65601536;
static constexpr size_t OFF_XCL  = 65675264;
static constexpr size_t OFF_SFB  = 222961664;
static constexpr size_t OFF_AGB  = 222994432;
static constexpr size_t WS_FULL  = 223256576;
static constexpr size_t WS_MIN   = 65675264;

__device__ __forceinline__ unsigned short f2bf(float f) {   // RNE
    unsigned int u = __float_as_uint(f);
    u += 0x7fff + ((u >> 16) & 1);
    return (unsigned short)(u >> 16);
}

// ---------------- K0: weight prep ----------------
__global__ __launch_bounds__(256) void k_prep(const float* __restrict__ sfw,
                                              const float* __restrict__ w1,
                                              const float* __restrict__ aggw,
                                              float* __restrict__ sfT,
                                              float* __restrict__ w1T,
                                              unsigned short* __restrict__ sfB,
                                              unsigned short* __restrict__ agB)
{
    int id = blockIdx.x * 256 + threadIdx.x;   // 182272 total
    if (id < 16384) {
        int cc = id >> 7, dd = id & 127;
        sfT[cc * 128 + dd] = sfw[dd * 128 + cc];
    } else if (id < 16384 + 18432) {
        int j = id - 16384;
        int o = j / 1152, r = j % 1152;
        int k = r >> 7, c = r & 127;
        w1T[j] = w1[o * 1152 + c * 9 + k];
    } else if (id < 16384 + 18432 + 16384) {
        int idx = id - (16384 + 18432);
        int j = idx & 7, lane = (idx >> 3) & 63, nt = (idx >> 9) & 7, kc32 = (idx >> 12) & 3;
        int k = kc32 * 32 + (lane >> 4) * 8 + j;
        int n = nt * 16 + (lane & 15);
        sfB[idx] = f2bf(sfw[n * 128 + k]);     // B[c][d] = sf_w[d][c]
    } else if (id < 16384 + 18432 + 16384 + 131072) {
        int idx = id - (16384 + 18432 + 16384);
        int local = idx & 16383, kc = idx >> 14;
        int j = local & 7, lane = (local >> 3) & 63, nt = (local >> 9) & 7, kc32 = (local >> 12) & 3;
        int k = kc * 128 + kc32 * 32 + (lane >> 4) * 8 + j;
        int n = nt * 16 + (lane & 15);
        agB[idx] = f2bf(aggw[(size_t)k * 128 + n]);
    }
}

// ---------------- K0b: NCHW -> NHWC transpose, float4 both sides ----------------
// 64 px x 128 ch per block; LDS tile[p][c] pitch 129 (writes 2-way=free, reads 4-way)
__global__ __launch_bounds__(256) void k_tr2(const float* __restrict__ x,
                                             float* __restrict__ xcl)
{
    const int b  = blockIdx.y;
    const int p0 = blockIdx.x * 64;
    const int t  = threadIdx.x;
    __shared__ float tile[64 * 129];

    {
        const int p4 = t & 15;              // f4 along pixels
        #pragma unroll
        for (int i = 0; i < 8; ++i) {
            const int c = i * 16 + (t >> 4);
            float4 v = *(const float4*)(x + ((size_t)(b * 128 + c)) * HWSZ + p0 + p4 * 4);
            tile[(4 * p4 + 0) * 129 + c] = v.x;
            tile[(4 * p4 + 1) * 129 + c] = v.y;
            tile[(4 * p4 + 2) * 129 + c] = v.z;
            tile[(4 * p4 + 3) * 129 + c] = v.w;
        }
    }
    __syncthreads();
    {
        const int c4 = t & 31;              // f4 along channels
        #pragma unroll
        for (int i = 0; i < 8; ++i) {
            const int p = i * 8 + (t >> 5);
            float4 v = {tile[p * 129 + 4 * c4 + 0], tile[p * 129 + 4 * c4 + 1],
                        tile[p * 129 + 4 * c4 + 2], tile[p * 129 + 4 * c4 + 3]};
            *(float4*)(xcl + ((size_t)b * HWSZ + p0 + p) * 128 + c4 * 4) = v;
        }
    }
}

// ---------------- K1a: offset conv+MLP, 16 kp/block, weights LDS-resident ---------
__global__ __launch_bounds__(256) void k_offsets2(
    const float* __restrict__ xcl, const float* __restrict__ kp,
    const float* __restrict__ w1T, const float* __restrict__ b1,
    const float* __restrict__ w2,  const float* __restrict__ b2,
    float* __restrict__ pos)
{
    const int t  = threadIdx.x;
    const int n0 = blockIdx.x * 16;

    __shared__ __align__(16) float wl[16 * 388];
    __shared__ __align__(16) float pl[16 * 388];
    __shared__ float o1l[16 * 16];
    __shared__ float kwl[16 * 2];

    if (t < 16) {
        const int n = n0 + t;
        float kx = kp[2 * n], ky = kp[2 * n + 1];
        kwl[t * 2 + 0] = (kx * 0.5f + 0.5f) * (float)(WW - 1);
        kwl[t * 2 + 1] = (ky * 0.5f + 0.5f) * (float)(HH - 1);
    }

    const int o_c  = t >> 4;
    const int kp_c = t & 15;

    float acc0 = 0.f, acc1 = 0.f;

    for (int h = 0; h < 3; ++h) {
        if (h) __syncthreads();
        #pragma unroll
        for (int i = 0; i < 6; ++i) {
            int idx = i * 256 + t;
            int o = idx / 96, c4 = idx % 96;
            *(float4*)&wl[o * 388 + c4 * 4] =
                *(const float4*)&w1T[o * 1152 + h * 384 + c4 * 4];
        }
        #pragma unroll
        for (int i = 0; i < 6; ++i) {
            int idx = i * 256 + t;
            int kk = idx / 96, r = idx % 96;
            int px = r >> 5, c4 = r & 31;
            int n = n0 + kk;
            int bi = n / NK;
            float kx = kp[2 * n], ky = kp[2 * n + 1];
            float kwx = (kx * 0.5f + 0.5f) * (float)(WW - 1);
            float kwy = (ky * 0.5f + 0.5f) * (float)(HH - 1);
            int cx = (int)((float)((int)kwx) - 0.5f);
            int cy = (int)((float)((int)kwy) - 0.5f);
            cx = min(max(cx, 0), WW - 4);
            cy = min(max(cy, 0), HH - 4);
            const float4* xb4 = (const float4*)xcl + (size_t)bi * HWSZ * 32;
            *(float4*)&pl[kk * 388 + r * 4] =
                xb4[((size_t)(cy + h) * WW + (cx + px)) * 32 + c4];
        }
        __syncthreads();
        #pragma unroll 4
        for (int q = 0; q < 96; q += 2) {
            float4 w0 = *(const float4*)&wl[o_c * 388 + q * 4];
            float4 p0 = *(const float4*)&pl[kp_c * 388 + q * 4];
            float4 w1v = *(const float4*)&wl[o_c * 388 + q * 4 + 4];
            float4 p1 = *(const float4*)&pl[kp_c * 388 + q * 4 + 4];
            acc0 = fmaf(w0.x, p0.x, fmaf(w0.y, p0.y, fmaf(w0.z, p0.z, fmaf(w0.w, p0.w, acc0))));
            acc1 = fmaf(w1v.x, p1.x, fmaf(w1v.y, p1.y, fmaf(w1v.z, p1.z, fmaf(w1v.w, p1.w, acc1))));
        }
    }

    o1l[kp_c * 16 + o_c] = fmaxf(acc0 + acc1 + b1[o_c], 0.f);
    __syncthreads();

    if (t < 128) {
        const int kk = t >> 3, j = t & 7;
        float sx = b2[j], sy = b2[8 + j];
        #pragma unroll
        for (int i = 0; i < 16; ++i) {
            float v = o1l[kk * 16 + i];
            sx = fmaf(v, w2[j * 16 + i], sx);
            sy = fmaf(v, w2[(8 + j) * 16 + i], sy);
        }
        sx = fminf(fmaxf(sx, -80.f), 80.f);
        sy = fminf(fmaxf(sy, -80.f), 80.f);
        float2 o = {kwl[kk * 2 + 0] + sx, kwl[kk * 2 + 1] + sy};
        ((float2*)pos)[(size_t)(n0 + kk) * 8 + j] = o;
    }
}

// ---------------- K1b: bilinear gather, barrier-free, bf16 out ----------------
__global__ __launch_bounds__(256) void k_gather(
    const float* __restrict__ xcl, const float* __restrict__ pos,
    unsigned short* __restrict__ fb)
{
    const int t = threadIdx.x;
    const int lane32 = t & 31;
    const int slot   = t >> 5;          // 0..7
    const int base   = blockIdx.x * 32;

    #pragma unroll
    for (int it = 0; it < 4; ++it) {
        const int s = base + it * 8 + slot;      // sample id 0..127999
        float2 P = ((const float2*)pos)[s];
        const int bi = s / (NK * NPOS);
        const float4* xb4 = (const float4*)xcl + (size_t)bi * HWSZ * 32;

        const float x0 = floorf(P.x), y0 = floorf(P.y);
        const float wx = P.x - x0, wy = P.y - y0;
        float4 acc = {0.f, 0.f, 0.f, 0.f};
        #pragma unroll
        for (int dy = 0; dy < 2; ++dy) {
            const float yc = y0 + (float)dy;
            const bool vy = (yc >= 0.f) && (yc <= (float)(HH - 1));
            const int  yi = (int)fminf(fmaxf(yc, 0.f), (float)(HH - 1));
            const float wyv = dy ? wy : (1.f - wy);
            #pragma unroll
            for (int dx = 0; dx < 2; ++dx) {
                const float xc = x0 + (float)dx;
                const bool vx = (xc >= 0.f) && (xc <= (float)(WW - 1));
                const int  xi = (int)fminf(fmaxf(xc, 0.f), (float)(WW - 1));
                const float wgt = (vx && vy) ? (dx ? wx : (1.f - wx)) * wyv : 0.f;
                float4 v = xb4[((size_t)yi * WW + xi) * 32 + lane32];
                acc.x = fmaf(v.x, wgt, acc.x);
                acc.y = fmaf(v.y, wgt, acc.y);
                acc.z = fmaf(v.z, wgt, acc.z);
                acc.w = fmaf(v.w, wgt, acc.w);
            }
        }
        ushort4 o = {f2bf(acc.x), f2bf(acc.y), f2bf(acc.z), f2bf(acc.w)};
        *(ushort4*)(fb + (size_t)s * 128 + lane32 * 4) = o;
    }
}

// ---------------- K2: fused sf+agg MFMA ----------------
// grid (250, 4). Block stages the 128 feats rows its agg K-chunk needs
// (local r = 2i+j <-> global feats row (m0+i)*8 + 2*kb + j), runs the sf GEMM
// (g rows = those same rows), selu -> bf16 into an LDS A-layout buffer
// Ag[64 kp][256 k] (k = j*128 + c), then the agg GEMM -> fp32 partials.
__global__ __launch_bounds__(256) void k_sfagg(
    const unsigned short* __restrict__ fb, const unsigned short* __restrict__ sfB,
    const unsigned short* __restrict__ agB, float* __restrict__ part)
{
    const int m0 = blockIdx.x * 64;
    const int kb = blockIdx.y;          // 0..3
    const int t  = threadIdx.x;
    __shared__ __align__(16) unsigned short Al[128 * 136];   // reused as Ag[64][264]

    const int w = t >> 6, l = t & 63;
    const int fr = l & 15, fq = l >> 4;

    // stage feats rows
    #pragma unroll
    for (int i = 0; i < 8; ++i) {
        int flat = i * 256 + t;
        int r = flat >> 4, c8 = flat & 15;
        *(short8*)(Al + r * 136 + c8 * 8) =
            *(const short8*)(fb + ((size_t)(m0 + (r >> 1)) * 8 + 2 * kb + (r & 1)) * 128 + c8 * 8);
    }
    __syncthreads();

    // sf GEMM: wave w -> g local rows [w*32, w*32+32)
    short8 a[2][4];
    #pragma unroll
    for (int mt = 0; mt < 2; ++mt)
        #pragma unroll
        for (int q = 0; q < 4; ++q)
            a[mt][q] = *(const short8*)(Al + (w * 32 + mt * 16 + fr) * 136 + q * 32 + fq * 8);

    f32x4 acc[2][8];
    #pragma unroll
    for (int mt = 0; mt < 2; ++mt)
        #pragma unroll
        for (int nt = 0; nt < 8; ++nt)
            #pragma unroll
            for (int r = 0; r < 4; ++r) acc[mt][nt][r] = 0.f;

    #pragma unroll 2
    for (int nt = 0; nt < 8; ++nt) {
        short8 b[4];
        #pragma unroll
        for (int q = 0; q < 4; ++q)
            b[q] = *(const short8*)(sfB + ((size_t)(q * 8 + nt) * 64 + l) * 8);
        #pragma unroll
        for (int mt = 0; mt < 2; ++mt)
            #pragma unroll
            for (int q = 0; q < 4; ++q)
                acc[mt][nt] = __builtin_amdgcn_mfma_f32_16x16x32_bf16(a[mt][q], b[q], acc[mt][nt], 0, 0, 0);
    }

    __syncthreads();   // all a-frag reads done; safe to overwrite Al as Ag

    // selu -> bf16 -> Ag[R>>1][(R&1)*128 + col], R = w*32 + mt*16 + fq*4 + r
    #pragma unroll
    for (int mt = 0; mt < 2; ++mt)
        #pragma unroll
        for (int nt = 0; nt < 8; ++nt)
            #pragma unroll
            for (int r = 0; r < 4; ++r) {
                float v = acc[mt][nt][r];
                float e = v > 0.f ? v : 1.6732632423543772f * expm1f(v);
                int R = w * 32 + mt * 16 + fq * 4 + r;
                Al[(R >> 1) * 264 + (R & 1) * 128 + nt * 16 + fr] =
                    f2bf(1.0507009873554805f * e);
            }
    __syncthreads();

    // agg GEMM: wave w -> kp rows [w*16, w*16+16), K = 256
    f32x4 acc2[8];
    #pragma unroll
    for (int nt = 0; nt < 8; ++nt)
        #pragma unroll
        for (int r = 0; r < 4; ++r) acc2[nt][r] = 0.f;

    #pragma unroll
    for (int j = 0; j < 2; ++j) {
        short8 a2[4];
        #pragma unroll
        for (int q = 0; q < 4; ++q)
            a2[q] = *(const short8*)(Al + (w * 16 + fr) * 264 + j * 128 + q * 32 + fq * 8);
        const unsigned short* Bb = agB + (size_t)(2 * kb + j) * 16384;
        #pragma unroll 2
        for (int nt = 0; nt < 8; ++nt) {
            short8 b[4];
            #pragma unroll
            for (int q = 0; q < 4; ++q)
                b[q] = *(const short8*)(Bb + ((size_t)(q * 8 + nt) * 64 + l) * 8);
            #pragma unroll
            for (int q = 0; q < 4; ++q)
                acc2[nt] = __builtin_amdgcn_mfma_f32_16x16x32_bf16(a2[q], b[q], acc2[nt], 0, 0, 0);
        }
    }

    float* Cb = part + (size_t)kb * NKP * 128 + (size_t)m0 * 128;
    #pragma unroll
    for (int nt = 0; nt < 8; ++nt)
        #pragma unroll
        for (int r = 0; r < 4; ++r)
            Cb[(size_t)(w * 16 + fq * 4 + r) * 128 + nt * 16 + fr] = acc2[nt][r];
}

// ---------------- K3: reduce 4 partials + L2 normalize ----------------
__global__ __launch_bounds__(256) void k_rn(const float* __restrict__ part,
                                            float* __restrict__ out)
{
    const int t = threadIdx.x;
    const int wv = t >> 6, l = t & 63;
    const int r = blockIdx.x * 4 + wv;
    float v0 = 0.f, v1 = 0.f;
    #pragma unroll
    for (int kc = 0; kc < 4; ++kc) {
        float2 v = *(const float2*)(part + ((size_t)kc * NKP + r) * 128 + 2 * l);
        v0 += v.x; v1 += v.y;
    }
    float s = v0 * v0 + v1 * v1;
    #pragma unroll
    for (int m = 32; m; m >>= 1) s += __shfl_xor(s, m);
    float inv = 1.f / fmaxf(sqrtf(s), 1e-12f);
    float2 o = {v0 * inv, v1 * inv};
    *(float2*)(out + (size_t)r * 128 + 2 * l) = o;
}

// ================= legacy fallback path (small ws) =================
__global__ __launch_bounds__(128) void k_sample(
    const float* __restrict__ x,  const float* __restrict__ kp,
    const float* __restrict__ w1, const float* __restrict__ b1,
    const float* __restrict__ w2, const float* __restrict__ b2,
    float* __restrict__ feats)
{
    const int n  = blockIdx.x;
    const int bi = n / NK;
    const int t  = threadIdx.x;

    __shared__ __align__(16) float patch[CH * 9];
    __shared__ float red[16 * 8];
    __shared__ float o1[16];
    __shared__ float offv[16];

    const float kx  = kp[(size_t)n * 2 + 0];
    const float ky  = kp[(size_t)n * 2 + 1];
    const float kwx = (kx * 0.5f + 0.5f) * (float)(WW - 1);
    const float kwy = (ky * 0.5f + 0.5f) * (float)(HH - 1);
    const int kwlx = (int)kwx;
    const int kwly = (int)kwy;
    int cx = (int)((float)kwlx - 0.5f);
    int cy = (int)((float)kwly - 0.5f);
    cx = min(max(cx, 0), WW - 1 - 3);
    cy = min(max(cy, 0), HH - 1 - 3);

    const float* xb = x + ((size_t)bi * CH + t) * HWSZ;
    {
        const float* p0 = xb + cy * WW + cx;
        #pragma unroll
        for (int i = 0; i < 3; ++i) {
            patch[t * 9 + i * 3 + 0] = p0[i * WW + 0];
            patch[t * 9 + i * 3 + 1] = p0[i * WW + 1];
            patch[t * 9 + i * 3 + 2] = p0[i * WW + 2];
        }
    }
    __syncthreads();
    {
        const int o = t & 15, g = t >> 4;
        const float4* wp = (const float4*)(w1 + o * 1152 + g * 144);
        const float4* pp = (const float4*)(patch + g * 144);
        float s = 0.f;
        #pragma unroll
        for (int q = 0; q < 36; ++q) {
            float4 wv = wp[q];
            float4 pv = pp[q];
            s = fmaf(wv.x, pv.x, fmaf(wv.y, pv.y, fmaf(wv.z, pv.z, fmaf(wv.w, pv.w, s))));
        }
        red[o * 8 + g] = s;
    }
    __syncthreads();
    if (t < 16) {
        float s = b1[t];
        #pragma unroll
        for (int g = 0; g < 8; ++g) s += red[t * 8 + g];
        o1[t] = fmaxf(s, 0.f);
    }
    __syncthreads();
    if (t < 16) {
        float s = b2[t];
        #pragma unroll
        for (int j = 0; j < 16; ++j) s = fmaf(o1[j], w2[t * 16 + j], s);
        offv[t] = fminf(fmaxf(s, -80.f), 80.f);
    }
    __syncthreads();

    #pragma unroll
    for (int p = 0; p < NPOS; ++p) {
        const float px = kwx + offv[p];
        const float py = kwy + offv[8 + p];
        const float x0 = floorf(px), y0 = floorf(py);
        const float wx = px - x0, wy = py - y0;
        float acc = 0.f;
        #pragma unroll
        for (int dy = 0; dy < 2; ++dy) {
            const float yc = y0 + (float)dy;
            const bool vy = (yc >= 0.f) && (yc <= (float)(HH - 1));
            const int  yi = (int)fminf(fmaxf(yc, 0.f), (float)(HH - 1));
            const float wyv = dy ? wy : (1.f - wy);
            #pragma unroll
            for (int dx = 0; dx < 2; ++dx) {
                const float xc = x0 + (float)dx;
                const bool vx = (xc >= 0.f) && (xc <= (float)(WW - 1));
                const int  xi = (int)fminf(fmaxf(xc, 0.f), (float)(WW - 1));
                const float wxv = dx ? wx : (1.f - wx);
                float v = xb[yi * WW + xi];
                v = (vx && vy) ? v : 0.f;
                acc = fmaf(v, wxv * wyv, acc);
            }
        }
        feats[((size_t)n * 8 + p) * CH + t] = acc;
    }
}

__global__ __launch_bounds__(256) void k_sf_legacy(float* __restrict__ gbuf,
                                                   const float* __restrict__ sfT)
{
    const int m0 = blockIdx.x * 64;
    const int t  = threadIdx.x;
    __shared__ __align__(16) float AT[128 * 68];

    #pragma unroll
    for (int i = 0; i < 32; ++i) {
        int flat = i * 256 + t;
        int mm = flat >> 7, kk = flat & 127;
        AT[kk * 68 + mm] = gbuf[(size_t)(m0 + mm) * 128 + kk];
    }
    __syncthreads();

    const int tx = t & 31, ty = t >> 5;
    const int d0 = tx * 4, mb = ty * 8;
    float acc[8][4];
    #pragma unroll
    for (int i = 0; i < 8; ++i)
        #pragma unroll
        for (int j = 0; j < 4; ++j) acc[i][j] = 0.f;

    #pragma unroll 4
    for (int k = 0; k < 128; ++k) {
        float4 a0 = *(const float4*)(AT + k * 68 + mb);
        float4 a1 = *(const float4*)(AT + k * 68 + mb + 4);
        float4 bq = *(const float4*)(sfT + k * 128 + d0);
        float a[8] = {a0.x, a0.y, a0.z, a0.w, a1.x, a1.y, a1.z, a1.w};
        float b4[4] = {bq.x, bq.y, bq.z, bq.w};
        #pragma unroll
        for (int i = 0; i < 8; ++i)
            #pragma unroll
            for (int j = 0; j < 4; ++j)
                acc[i][j] = fmaf(a[i], b4[j], acc[i][j]);
    }

    #pragma unroll
    for (int i = 0; i < 8; ++i) {
        float4 o;
        float* ov = &o.x;
        #pragma unroll
        for (int j = 0; j < 4; ++j) {
            float v = acc[i][j];
            float r = v > 0.f ? v : 1.6732632423543772f * expm1f(v);
            ov[j] = 1.0507009873554805f * r;
        }
        *(float4*)(gbuf + (size_t)(m0 + mb + i) * 128 + d0) = o;
    }
}

__global__ __launch_bounds__(256) void k_agg_mono(const float* __restrict__ gbuf,
                                                  const float* __restrict__ aggw,
                                                  float* __restrict__ out)
{
    const int m0 = blockIdx.x * 64;
    const int t  = threadIdx.x;
    __shared__ __align__(16) float AT[128 * 68];

    const int tx = t & 31, ty = t >> 5;
    const int d0 = tx * 4, mb = ty * 8;
    float acc[8][4];
    #pragma unroll
    for (int i = 0; i < 8; ++i)
        #pragma unroll
        for (int j = 0; j < 4; ++j) acc[i][j] = 0.f;

    for (int kc = 0; kc < 8; ++kc) {
        __syncthreads();
        #pragma unroll
        for (int i = 0; i < 32; ++i) {
            int flat = i * 256 + t;
            int mm = flat >> 7, kk = flat & 127;
            AT[kk * 68 + mm] = gbuf[(size_t)(m0 + mm) * 1024 + kc * 128 + kk];
        }
        __syncthreads();
        #pragma unroll 4
        for (int kk = 0; kk < 128; ++kk) {
            float4 a0 = *(const float4*)(AT + kk * 68 + mb);
            float4 a1 = *(const float4*)(AT + kk * 68 + mb + 4);
            float4 bq = *(const float4*)(aggw + (size_t)(kc * 128 + kk) * 128 + d0);
            float a[8] = {a0.x, a0.y, a0.z, a0.w, a1.x, a1.y, a1.z, a1.w};
            float b4[4] = {bq.x, bq.y, bq.z, bq.w};
            #pragma unroll
            for (int i = 0; i < 8; ++i)
                #pragma unroll
                for (int j = 0; j < 4; ++j)
                    acc[i][j] = fmaf(a[i], b4[j], acc[i][j]);
        }
    }

    #pragma unroll
    for (int i = 0; i < 8; ++i) {
        float s = acc[i][0] * acc[i][0] + acc[i][1] * acc[i][1]
                + acc[i][2] * acc[i][2] + acc[i][3] * acc[i][3];
        #pragma unroll
        for (int m = 16; m; m >>= 1) s += __shfl_xor(s, m);
        const float inv = 1.f / fmaxf(sqrtf(s), 1e-12f);
        float4 o = {acc[i][0] * inv, acc[i][1] * inv, acc[i][2] * inv, acc[i][3] * inv};
        *(float4*)(out + (size_t)(m0 + mb + i) * 128 + d0) = o;
    }
}

extern "C" void kernel_launch(void* const* d_in, const int* in_sizes, int n_in,
                              void* d_out, int out_size, void* d_ws, size_t ws_size,
                              hipStream_t stream)
{
    const float* x   = (const float*)d_in[0];
    const float* kp  = (const float*)d_in[1];
    const float* w1  = (const float*)d_in[2];
    const float* b1  = (const float*)d_in[3];
    const float* w2  = (const float*)d_in[4];
    const float* b2  = (const float*)d_in[5];
    const float* sfw = (const float*)d_in[6];
    const float* agg = (const float*)d_in[7];
    float* out = (float*)d_out;

    if (ws_size < WS_MIN) return;

    char*  ws    = (char*)d_ws;
    unsigned short* fb = (unsigned short*)ws;           // feats bf16 [128000][128]
    float* pos   = (float*)(ws + OFF_POS);              // [16000][8][2]
    float* sfT   = (float*)(ws + OFF_SFT);
    float* w1T   = (float*)(ws + OFF_W1T);
    float* xcl   = (float*)(ws + OFF_XCL);              // NHWC x
    float* part  = (float*)(ws + OFF_XCL);              // aliases xcl (dead after gather)
    unsigned short* sfB = (unsigned short*)(ws + OFF_SFB);
    unsigned short* agB = (unsigned short*)(ws + OFF_AGB);

    k_prep<<<712, 256, 0, stream>>>(sfw, w1, agg, sfT, w1T, sfB, agB);

    if (ws_size >= WS_FULL) {
        k_tr2     <<<dim3(HWSZ / 64, BB), 256, 0, stream>>>(x, xcl);
        k_offsets2<<<NKP / 16, 256, 0, stream>>>(xcl, kp, w1T, b1, w2, b2, pos);
        k_gather  <<<4000, 256, 0, stream>>>(xcl, pos, fb);
        k_sfagg   <<<dim3(250, 4), 256, 0, stream>>>(fb, sfB, agB, part);
        k_rn      <<<4000, 256, 0, stream>>>(part, out);
    } else {
        float* feats = (float*)ws;
        k_sample   <<<NKP, 128, 0, stream>>>(x, kp, w1, b1, w2, b2, feats);
        k_sf_legacy<<<2000, 256, 0, stream>>>(feats, sfT);
        k_agg_mono <<<250,  256, 0, stream>>>(feats, agg, out);
    }
}